// Round 6
// baseline (357.797 us; speedup 1.0000x reference)
//
#include <hip/hip_runtime.h>
#include <hip/hip_bf16.h>

#define NN 100000
#define EE 1600000
#define NBK 196      // buckets = ceil(N / 512)
#define BSH 9        // bucket shift: 512 nodes per bucket
#define EPB 4096     // edges per block in binA/bhist
#define STG 10240    // binB LDS staging entries

using frag8 = __attribute__((ext_vector_type(8))) short;
using f32x4 = __attribute__((ext_vector_type(4))) float;

__device__ inline unsigned short f2bf(float f) {
    unsigned u = __float_as_uint(f);
    u = u + 0x7FFFu + ((u >> 16) & 1u);   // RNE
    return (unsigned short)(u >> 16);
}
__device__ inline float bf2f(unsigned short u) {
    return __uint_as_float(((unsigned)u) << 16);
}
__device__ inline unsigned pack_bf16(float a, float b) {
    __hip_bfloat162 h = __float22bfloat162_rn(float2{a, b});
    union { __hip_bfloat162 h2; unsigned u; } c;
    c.h2 = h;
    return c.u;
}
__device__ inline unsigned char f2fp8(float v) {
    unsigned p = __builtin_amdgcn_cvt_pk_fp8_f32(v, v, 0, false);
    return (unsigned char)(p & 0xff);
}
__device__ inline float fp82f(unsigned v) {
    return __builtin_amdgcn_cvt_f32_fp8(v, 0);
}

// ---------------- CSR build: bucketed, write-coalesced ----------------

__global__ __launch_bounds__(256) void bhist_k(const int* __restrict__ d1,
                                               const int* __restrict__ d2,
                                               int* __restrict__ bcnt) {
    __shared__ int lh[NBK];
    int adj = blockIdx.y;
    const int* dd = adj ? d2 : d1;
    int t = threadIdx.x;
    for (int i = t; i < NBK; i += 256) lh[i] = 0;
    __syncthreads();
    int e0 = blockIdx.x * EPB;
    #pragma unroll
    for (int k = 0; k < 16; ++k) {
        int e = e0 + k * 256 + t;
        if (e < EE) atomicAdd(&lh[dd[e] >> BSH], 1);
    }
    __syncthreads();
    for (int i = t; i < NBK; i += 256)
        if (lh[i]) atomicAdd(&bcnt[adj * NBK + i], lh[i]);
}

__global__ __launch_bounds__(256) void bscan_k(const int* __restrict__ bcnt,
                                               int* __restrict__ bbase,
                                               int* __restrict__ bcur) {
    int adj = blockIdx.x;
    __shared__ int s[256];
    int t = threadIdx.x;
    int v = (t < NBK) ? bcnt[adj * NBK + t] : 0;
    s[t] = v;
    __syncthreads();
    for (int off = 1; off < 256; off <<= 1) {
        int u = (t >= off) ? s[t - off] : 0;
        __syncthreads();
        s[t] += u;
        __syncthreads();
    }
    if (t < NBK) {
        int ex = s[t] - v;
        bbase[adj * (NBK + 1) + t] = ex;
        bcur[adj * NBK + t] = ex;
    }
    if (t == NBK - 1) bbase[adj * (NBK + 1) + NBK] = s[t];
}

__global__ __launch_bounds__(256) void binA_k(const int* __restrict__ s1,
                                              const int* __restrict__ d1,
                                              const int* __restrict__ s2,
                                              const int* __restrict__ d2,
                                              int* __restrict__ bcur,
                                              uint2* __restrict__ tmp1,
                                              uint2* __restrict__ tmp2) {
    __shared__ int lhist[NBK], lbase[NBK], gbase[NBK], lcur[NBK];
    __shared__ int sscan[256];
    __shared__ int stot;
    __shared__ uint2 stage[EPB];
    int adj = blockIdx.y;
    const int* ss = adj ? s2 : s1;
    const int* dd = adj ? d2 : d1;
    uint2* tmp = adj ? tmp2 : tmp1;
    int t = threadIdx.x;
    for (int i = t; i < NBK; i += 256) { lhist[i] = 0; lcur[i] = 0; }
    __syncthreads();
    int e0 = blockIdx.x * EPB;
    int d[16], s[16];
    #pragma unroll
    for (int k = 0; k < 16; ++k) {
        int e = e0 + k * 256 + t;
        d[k] = (e < EE) ? dd[e] : -1;
        s[k] = (e < EE) ? ss[e] : 0;
        if (d[k] >= 0) atomicAdd(&lhist[d[k] >> BSH], 1);
    }
    __syncthreads();
    int hv = (t < NBK) ? lhist[t] : 0;
    sscan[t] = hv;
    __syncthreads();
    for (int off = 1; off < 256; off <<= 1) {
        int u = (t >= off) ? sscan[t - off] : 0;
        __syncthreads();
        sscan[t] += u;
        __syncthreads();
    }
    if (t < NBK) lbase[t] = sscan[t] - hv;
    if (t == NBK - 1) stot = sscan[t];
    __syncthreads();
    for (int i = t; i < NBK; i += 256)
        gbase[i] = lhist[i] ? atomicAdd(&bcur[adj * NBK + i], lhist[i]) : 0;
    __syncthreads();
    #pragma unroll
    for (int k = 0; k < 16; ++k) {
        if (d[k] >= 0) {
            int b = d[k] >> BSH;
            int pos = lbase[b] + atomicAdd(&lcur[b], 1);
            stage[pos] = make_uint2((unsigned)d[k], (unsigned)s[k]);
        }
    }
    __syncthreads();
    int tot = stot;
    for (int i = t; i < tot; i += 256) {
        uint2 u = stage[i];
        int b = u.x >> BSH;
        tmp[gbase[b] + (i - lbase[b])] = u;   // chunk-coalesced
    }
}

__global__ __launch_bounds__(256) void binB_k(const uint2* __restrict__ tmp1,
                                              const uint2* __restrict__ tmp2,
                                              const int* __restrict__ bbase,
                                              int* __restrict__ rs1,
                                              int* __restrict__ rs2,
                                              int* __restrict__ csr1,
                                              int* __restrict__ csr2) {
    __shared__ int cnt[512], cur[512];
    __shared__ int sscan[256];
    __shared__ int stage[STG];
    int adj = blockIdx.y, b = blockIdx.x;
    const uint2* tmp = adj ? tmp2 : tmp1;
    int* rs  = adj ? rs2  : rs1;
    int* csr = adj ? csr2 : csr1;
    int t = threadIdx.x;
    int n0 = b << BSH;
    int n1 = n0 + 512; if (n1 > NN) n1 = NN;
    int nn = n1 - n0;
    int base = bbase[adj * (NBK + 1) + b];
    int count = bbase[adj * (NBK + 1) + b + 1] - base;
    cnt[t] = 0; cnt[t + 256] = 0;
    __syncthreads();
    for (int i = t; i < count; i += 256)
        atomicAdd(&cnt[tmp[base + i].x - n0], 1);
    __syncthreads();
    int c0 = cnt[2 * t], c1 = cnt[2 * t + 1];
    int ps = c0 + c1;
    sscan[t] = ps;
    __syncthreads();
    for (int off = 1; off < 256; off <<= 1) {
        int u = (t >= off) ? sscan[t - off] : 0;
        __syncthreads();
        sscan[t] += u;
        __syncthreads();
    }
    int pe = sscan[t] - ps;
    int e0x = pe, e1x = pe + c0;
    if (2 * t < nn)     rs[n0 + 2 * t]     = base + e0x;
    if (2 * t + 1 < nn) rs[n0 + 2 * t + 1] = base + e1x;
    cur[2 * t] = e0x; cur[2 * t + 1] = e1x;
    if (t == 0 && n1 == NN) rs[NN] = base + count;
    __syncthreads();
    for (int i = t; i < count; i += 256) {
        uint2 u = tmp[base + i];
        int loc = atomicAdd(&cur[u.x - n0], 1);
        if (loc < STG) stage[loc] = (int)u.y;
        else csr[base + loc] = (int)u.y;
    }
    __syncthreads();
    int m = count < STG ? count : STG;
    for (int i = t; i < m; i += 256) csr[base + i] = stage[i];
}

// ---------------- W_embed fp32 -> bf16, transposed + chunk-swizzled ----------------

__global__ void wconv_k(const float* __restrict__ W, unsigned short* __restrict__ Wbf) {
    int id = blockIdx.x * 256 + threadIdx.x;
    if (id < 512 * 64) {
        int k = id >> 6, col = id & 63;   // W row-major [512][64]
        int ch = k >> 3, el = k & 7;
        int cs = (ch & ~15) | ((ch & 15) ^ (col & 7));
        Wbf[col * 512 + cs * 8 + el] = f2bf(W[id]);
    }
}

// ---------------- W_cls -> Wbig bf16 [128 cols][192 k], 8-chunk-group swizzle ----------------

__global__ void wcls_k(const float* __restrict__ Wc, unsigned short* __restrict__ Wbig) {
    int id = blockIdx.x * 256 + threadIdx.x;   // 192*128
    int k = id >> 7, col = id & 127;
    float v = 0.f;
    if (col < 40) v = Wc[k * 40 + col];
    else if (col < 80)  { if (k >= 64) v = Wc[(192 + k - 64) * 40 + (col - 40)]; }
    else if (col < 120) { if (k >= 64) v = Wc[(320 + k - 64) * 40 + (col - 80)]; }
    int ch = k >> 3, el = k & 7;
    int phys = (ch & ~7) | ((ch & 7) ^ (col & 7));
    Wbig[col * 192 + phys * 8 + el] = f2bf(v);
}

// ---------------- embed: hcat[:,0:64] = relu(x @ W + b); also fp8 copy h0f8 ----------------

__global__ __launch_bounds__(256) void embed_k(const float* __restrict__ x,
                                               const unsigned short* __restrict__ Wbf,
                                               const float* __restrict__ bias,
                                               unsigned short* __restrict__ hcat,
                                               unsigned char* __restrict__ h0f8) {
    __shared__ unsigned short sA[64 * 128];
    __shared__ unsigned short sW[64 * 128];
    int tid = threadIdx.x;
    int lane = tid & 63, wave = tid >> 6;
    int row0 = blockIdx.x * 64;
    f32x4 acc[4];
    #pragma unroll
    for (int n = 0; n < 4; n++) acc[n] = (f32x4){0.f, 0.f, 0.f, 0.f};

    int ccol = tid & 15;
    int rbase = tid >> 4;

    for (int kt = 0; kt < 4; ++kt) {
        #pragma unroll
        for (int rr = 0; rr < 4; ++rr) {
            int r = rbase + rr * 16;
            int grow = row0 + r;
            float v[8];
            if (grow < NN) {
                const float4* px = (const float4*)(x + (size_t)grow * 512 + kt * 128 + ccol * 8);
                float4 p0 = px[0], p1 = px[1];
                v[0] = p0.x; v[1] = p0.y; v[2] = p0.z; v[3] = p0.w;
                v[4] = p1.x; v[5] = p1.y; v[6] = p1.z; v[7] = p1.w;
            } else {
                #pragma unroll
                for (int i = 0; i < 8; i++) v[i] = 0.f;
            }
            unsigned uu[4];
            #pragma unroll
            for (int i = 0; i < 4; i++)
                uu[i] = pack_bf16(v[2 * i], v[2 * i + 1]);
            int cs = ccol ^ (r & 7);
            uint4 pk; pk.x = uu[0]; pk.y = uu[1]; pk.z = uu[2]; pk.w = uu[3];
            *(uint4*)&sA[(r * 16 + cs) * 8] = pk;
        }
        for (int q = tid; q < 1024; q += 256) {
            int col = q >> 4, c = q & 15;
            ((uint4*)sW)[q] = ((const uint4*)Wbf)[col * 64 + kt * 16 + c];
        }
        __syncthreads();
        #pragma unroll
        for (int kk = 0; kk < 4; ++kk) {
            int ar = wave * 16 + (lane & 15);
            int ac = (kk * 4 + (lane >> 4)) ^ (ar & 7);
            frag8 a = *(const frag8*)&sA[(ar * 16 + ac) * 8];
            #pragma unroll
            for (int n = 0; n < 4; n++) {
                int col = n * 16 + (lane & 15);
                int bc = (kk * 4 + (lane >> 4)) ^ (col & 7);
                frag8 b = *(const frag8*)&sW[(col * 16 + bc) * 8];
                acc[n] = __builtin_amdgcn_mfma_f32_16x16x32_bf16(a, b, acc[n], 0, 0, 0);
            }
        }
        __syncthreads();
    }
    #pragma unroll
    for (int n = 0; n < 4; n++) {
        int col = n * 16 + (lane & 15);
        float bv = bias[col];
        #pragma unroll
        for (int i = 0; i < 4; i++) {
            int r = row0 + wave * 16 + (lane >> 4) * 4 + i;
            if (r < NN) {
                float vv = acc[n][i] + bv;
                vv = vv > 0.f ? vv : 0.f;
                hcat[(size_t)r * 192 + col] = f2bf(vv);
                h0f8[(size_t)r * 64 + col] = f2fp8(vv);
            }
        }
    }
}

// ---------------- round 1: hcat[:,64:192] = [A1·h0 | A2·h0], gather fp8 h0 (1 line/edge) ----------------

__device__ inline float gatherF8(const unsigned char* __restrict__ h8,
                                 const int* __restrict__ csr, int s, int e, int lane) {
    float acc = 0.f;
    for (int t0 = s; t0 < e; t0 += 64) {
        int rem = e - t0;
        int idxv = 0;
        if (lane < rem) idxv = csr[t0 + lane];
        int cnt = rem < 64 ? rem : 64;
        int j = 0;
        for (; j + 8 <= cnt; j += 8) {
            int s0 = __shfl(idxv, j),     s1 = __shfl(idxv, j + 1);
            int s2 = __shfl(idxv, j + 2), s3 = __shfl(idxv, j + 3);
            int s4 = __shfl(idxv, j + 4), s5 = __shfl(idxv, j + 5);
            int s6 = __shfl(idxv, j + 6), s7 = __shfl(idxv, j + 7);
            unsigned v0 = h8[(size_t)s0 * 64 + lane];
            unsigned v1 = h8[(size_t)s1 * 64 + lane];
            unsigned v2 = h8[(size_t)s2 * 64 + lane];
            unsigned v3 = h8[(size_t)s3 * 64 + lane];
            unsigned v4 = h8[(size_t)s4 * 64 + lane];
            unsigned v5 = h8[(size_t)s5 * 64 + lane];
            unsigned v6 = h8[(size_t)s6 * 64 + lane];
            unsigned v7 = h8[(size_t)s7 * 64 + lane];
            acc += ((fp82f(v0) + fp82f(v1)) + (fp82f(v2) + fp82f(v3)))
                 + ((fp82f(v4) + fp82f(v5)) + (fp82f(v6) + fp82f(v7)));
        }
        for (; j < cnt; ++j) {
            int s0 = __shfl(idxv, j);
            acc += fp82f((unsigned)h8[(size_t)s0 * 64 + lane]);
        }
    }
    return acc;
}

__global__ __launch_bounds__(256) void round1_k(const unsigned char* __restrict__ h0f8,
                                                unsigned short* hc,
                                                const int* __restrict__ rs1,
                                                const int* __restrict__ csr1,
                                                const int* __restrict__ rs2,
                                                const int* __restrict__ csr2) {
    int wave = threadIdx.x >> 6, lane = threadIdx.x & 63;
    int row = blockIdx.x * 4 + wave;

    float a1 = gatherF8(h0f8, csr1, rs1[row], rs1[row + 1], lane);
    float a2 = gatherF8(h0f8, csr2, rs2[row], rs2[row + 1], lane);

    hc[(size_t)row * 192 + 64 + lane]  = f2bf(a1);
    hc[(size_t)row * 192 + 128 + lane] = f2bf(a2);
}

// ---------------- gemm: [logits | z1 | z2] = hcat(Nx192) @ Wbig(192x120); z -> fp8 ----------------

__global__ __launch_bounds__(256) void gemm_k(const unsigned short* __restrict__ hcat,
                                              const unsigned short* __restrict__ Wbig,
                                              const float* __restrict__ bc,
                                              float* __restrict__ logits,
                                              unsigned char* __restrict__ zf8) {
    __shared__ unsigned short sA[64 * 64];
    __shared__ unsigned short sB[128 * 64];
    int tid = threadIdx.x;
    int lane = tid & 63, wave = tid >> 6;
    int row0 = blockIdx.x * 64;
    f32x4 acc[8];
    #pragma unroll
    for (int n = 0; n < 8; n++) acc[n] = (f32x4){0.f, 0.f, 0.f, 0.f};

    for (int kt = 0; kt < 3; ++kt) {
        #pragma unroll
        for (int q = tid; q < 512; q += 256) {
            int r = q >> 3, c = q & 7;
            int phys = c ^ (r & 7);
            ((uint4*)sA)[r * 8 + phys] = ((const uint4*)hcat)[(size_t)(row0 + r) * 24 + kt * 8 + c];
        }
        #pragma unroll
        for (int q = tid; q < 1024; q += 256) {
            int col = q >> 3, c = q & 7;
            ((uint4*)sB)[q] = ((const uint4*)Wbig)[col * 24 + kt * 8 + c];
        }
        __syncthreads();
        #pragma unroll
        for (int kk = 0; kk < 2; ++kk) {
            int ar = wave * 16 + (lane & 15);
            int ac = (kk * 4 + (lane >> 4)) ^ (ar & 7);
            frag8 a = *(const frag8*)&sA[(ar * 8 + ac) * 8];
            #pragma unroll
            for (int n = 0; n < 8; n++) {
                int col = n * 16 + (lane & 15);
                int bcc = (kk * 4 + (lane >> 4)) ^ (col & 7);
                frag8 b = *(const frag8*)&sB[(col * 8 + bcc) * 8];
                acc[n] = __builtin_amdgcn_mfma_f32_16x16x32_bf16(a, b, acc[n], 0, 0, 0);
            }
        }
        __syncthreads();
    }
    #pragma unroll
    for (int n = 0; n < 8; n++) {
        int col = n * 16 + (lane & 15);
        float bv = (col < 40) ? bc[col] : 0.f;
        #pragma unroll
        for (int i = 0; i < 4; i++) {
            int r = row0 + wave * 16 + (lane >> 4) * 4 + i;
            if (r < NN) {
                float vv = acc[n][i];
                if (col < 40) {
                    logits[(size_t)r * 40 + col] = vv + bv;
                } else if (col < 80) {
                    zf8[(size_t)r * 128 + (col - 40)] = f2fp8(vv);        // z1: bytes 0..39
                } else if (col < 120) {
                    zf8[(size_t)r * 128 + 64 + (col - 80)] = f2fp8(vv);   // z2: bytes 64..103
                }
            }
        }
    }
}

// ---------------- round 2: logits += A1·z1 + A2·z2; log_softmax (fp8 z, 1 line/edge) ----------------

__device__ inline float gatherZ8(const unsigned char* __restrict__ z8, int zoff,
                                 const int* __restrict__ csr, int s, int e, int lane) {
    float acc = 0.f;
    for (int t0 = s; t0 < e; t0 += 64) {
        int rem = e - t0;
        int idxv = 0;
        if (lane < rem) idxv = csr[t0 + lane];
        int cnt = rem < 64 ? rem : 64;
        int j = 0;
        for (; j + 8 <= cnt; j += 8) {
            int s0 = __shfl(idxv, j),     s1 = __shfl(idxv, j + 1);
            int s2 = __shfl(idxv, j + 2), s3 = __shfl(idxv, j + 3);
            int s4 = __shfl(idxv, j + 4), s5 = __shfl(idxv, j + 5);
            int s6 = __shfl(idxv, j + 6), s7 = __shfl(idxv, j + 7);
            unsigned v0 = z8[(size_t)s0 * 128 + zoff + lane];
            unsigned v1 = z8[(size_t)s1 * 128 + zoff + lane];
            unsigned v2 = z8[(size_t)s2 * 128 + zoff + lane];
            unsigned v3 = z8[(size_t)s3 * 128 + zoff + lane];
            unsigned v4 = z8[(size_t)s4 * 128 + zoff + lane];
            unsigned v5 = z8[(size_t)s5 * 128 + zoff + lane];
            unsigned v6 = z8[(size_t)s6 * 128 + zoff + lane];
            unsigned v7 = z8[(size_t)s7 * 128 + zoff + lane];
            acc += ((fp82f(v0) + fp82f(v1)) + (fp82f(v2) + fp82f(v3)))
                 + ((fp82f(v4) + fp82f(v5)) + (fp82f(v6) + fp82f(v7)));
        }
        for (; j < cnt; ++j) {
            int s0 = __shfl(idxv, j);
            acc += fp82f((unsigned)z8[(size_t)s0 * 128 + zoff + lane]);
        }
    }
    return acc;
}

__global__ __launch_bounds__(256) void round2_k(const unsigned char* __restrict__ zf8,
                                                const int* __restrict__ rs1,
                                                const int* __restrict__ csr1,
                                                const int* __restrict__ rs2,
                                                const int* __restrict__ csr2,
                                                float* __restrict__ logits) {
    int wave = threadIdx.x >> 6, lane = threadIdx.x & 63;
    int row = blockIdx.x * 4 + wave;

    float acc = gatherZ8(zf8, 0,  csr1, rs1[row], rs1[row + 1], lane)
              + gatherZ8(zf8, 64, csr2, rs2[row], rs2[row + 1], lane);

    float v = -1e30f;
    if (lane < 40) v = logits[(size_t)row * 40 + lane] + acc;
    float m = v;
    #pragma unroll
    for (int off = 32; off; off >>= 1) m = fmaxf(m, __shfl_xor(m, off));
    float ex = (lane < 40) ? __expf(v - m) : 0.f;
    float ssum = ex;
    #pragma unroll
    for (int off = 32; off; off >>= 1) ssum += __shfl_xor(ssum, off);
    float ls = __logf(ssum);
    if (lane < 40) logits[(size_t)row * 40 + lane] = v - m - ls;
}

// ---------------- launch ----------------

extern "C" void kernel_launch(void* const* d_in, const int* in_sizes, int n_in,
                              void* d_out, int out_size, void* d_ws, size_t ws_size,
                              hipStream_t stream) {
    const float* x       = (const float*)d_in[0];
    const float* W_embed = (const float*)d_in[1];
    const float* b_embed = (const float*)d_in[2];
    const float* W_cls   = (const float*)d_in[3];
    const float* b_cls   = (const float*)d_in[4];
    const int* a1src = (const int*)d_in[5];
    const int* a1dst = (const int*)d_in[6];
    const int* a2src = (const int*)d_in[7];
    const int* a2dst = (const int*)d_in[8];

    float* logits = (float*)d_out;
    float* ws = (float*)d_ws;

    // ws layout (units: 4B elements)
    const size_t OFF_HCAT = 0;          // N*192 bf16 = 9.6M floats (overlays tmp1/tmp2: 6.4M floats)
    const size_t OFF_ZF8  = 9600000;    // N*128 bytes = 3.2M floats
    const size_t OFF_H0F8 = 12800000;   // N*64 bytes = 1.6M floats
    const size_t OFF_RS1  = 14400000;   // N+1 ints
    const size_t OFF_RS2  = 14500004;   // N+1 ints
    const size_t OFF_BB   = 14600008;   // bucketBase 2 x 197
    const size_t OFF_BC   = 14600402;   // bcur 2 x 196
    const size_t OFF_BCNT = 14600794;   // bucketCnt 2 x 196
    const size_t OFF_CSR1 = 14601188;   // E ints
    const size_t OFF_CSR2 = 16201188;   // E ints
    const size_t OFF_WBF  = 17801188;   // 32768 ushorts
    const size_t OFF_WBIG = 17817572;   // 24576 ushorts

    unsigned short* hcat = (unsigned short*)(ws + OFF_HCAT);
    unsigned char*  zf8  = (unsigned char*)(ws + OFF_ZF8);
    unsigned char*  h0f8 = (unsigned char*)(ws + OFF_H0F8);
    uint2* tmp1 = (uint2*)(ws + OFF_HCAT);        // overlay: used only before embed
    uint2* tmp2 = tmp1 + EE;
    int* rs1   = (int*)(ws + OFF_RS1);
    int* rs2   = (int*)(ws + OFF_RS2);
    int* bbase = (int*)(ws + OFF_BB);
    int* bcur  = (int*)(ws + OFF_BC);
    int* bcnt  = (int*)(ws + OFF_BCNT);
    int* csr1  = (int*)(ws + OFF_CSR1);
    int* csr2  = (int*)(ws + OFF_CSR2);
    unsigned short* wbf  = (unsigned short*)(ws + OFF_WBF);
    unsigned short* wbig = (unsigned short*)(ws + OFF_WBIG);

    hipMemsetAsync(ws + OFF_BCNT, 0, 392 * 4, stream);

    const int NBA = (EE + EPB - 1) / EPB;   // 391

    bhist_k<<<dim3(NBA, 2), 256, 0, stream>>>(a1dst, a2dst, bcnt);
    bscan_k<<<2, 256, 0, stream>>>(bcnt, bbase, bcur);
    binA_k<<<dim3(NBA, 2), 256, 0, stream>>>(a1src, a1dst, a2src, a2dst, bcur, tmp1, tmp2);
    binB_k<<<dim3(NBK, 2), 256, 0, stream>>>(tmp1, tmp2, bbase, rs1, rs2, csr1, csr2);

    wconv_k<<<128, 256, 0, stream>>>(W_embed, wbf);
    wcls_k<<<96, 256, 0, stream>>>(W_cls, wbig);
    embed_k<<<(NN + 63) / 64, 256, 0, stream>>>(x, wbf, b_embed, hcat, h0f8);

    round1_k<<<NN / 4, 256, 0, stream>>>(h0f8, hcat, rs1, csr1, rs2, csr2);
    gemm_k<<<(NN + 63) / 64, 256, 0, stream>>>(hcat, wbig, b_cls, logits, zf8);
    round2_k<<<NN / 4, 256, 0, stream>>>(zf8, rs1, csr1, rs2, csr2, logits);
}

// Round 7
// 308.843 us; speedup vs baseline: 1.1585x; 1.1585x over previous
//
#include <hip/hip_runtime.h>
#include <hip/hip_bf16.h>

#define NN 100000
#define EE 1600000
#define NBK 196      // buckets = ceil(N / 512)
#define BSH 9        // bucket shift: 512 nodes per bucket
#define EPB 4096     // edges per block in binA/bhist
#define STG 10240    // binB LDS staging entries

using frag8 = __attribute__((ext_vector_type(8))) short;
using f32x4 = __attribute__((ext_vector_type(4))) float;

__device__ inline unsigned short f2bf(float f) {
    unsigned u = __float_as_uint(f);
    u = u + 0x7FFFu + ((u >> 16) & 1u);   // RNE
    return (unsigned short)(u >> 16);
}
__device__ inline float bf2f(unsigned short u) {
    return __uint_as_float(((unsigned)u) << 16);
}
__device__ inline unsigned pack_bf16(float a, float b) {
    __hip_bfloat162 h = __float22bfloat162_rn(float2{a, b});
    union { __hip_bfloat162 h2; unsigned u; } c;
    c.h2 = h;
    return c.u;
}

// ---------------- CSR build: bucketed, write-coalesced ----------------

__global__ __launch_bounds__(256) void bhist_k(const int* __restrict__ d1,
                                               const int* __restrict__ d2,
                                               int* __restrict__ bcnt) {
    __shared__ int lh[NBK];
    int adj = blockIdx.y;
    const int* dd = adj ? d2 : d1;
    int t = threadIdx.x;
    for (int i = t; i < NBK; i += 256) lh[i] = 0;
    __syncthreads();
    int e0 = blockIdx.x * EPB;
    #pragma unroll
    for (int k = 0; k < 16; ++k) {
        int e = e0 + k * 256 + t;
        if (e < EE) atomicAdd(&lh[dd[e] >> BSH], 1);
    }
    __syncthreads();
    for (int i = t; i < NBK; i += 256)
        if (lh[i]) atomicAdd(&bcnt[adj * NBK + i], lh[i]);
}

__global__ __launch_bounds__(256) void bscan_k(const int* __restrict__ bcnt,
                                               int* __restrict__ bbase,
                                               int* __restrict__ bcur) {
    int adj = blockIdx.x;
    __shared__ int s[256];
    int t = threadIdx.x;
    int v = (t < NBK) ? bcnt[adj * NBK + t] : 0;
    s[t] = v;
    __syncthreads();
    for (int off = 1; off < 256; off <<= 1) {
        int u = (t >= off) ? s[t - off] : 0;
        __syncthreads();
        s[t] += u;
        __syncthreads();
    }
    if (t < NBK) {
        int ex = s[t] - v;
        bbase[adj * (NBK + 1) + t] = ex;
        bcur[adj * NBK + t] = ex;
    }
    if (t == NBK - 1) bbase[adj * (NBK + 1) + NBK] = s[t];
}

__global__ __launch_bounds__(256) void binA_k(const int* __restrict__ s1,
                                              const int* __restrict__ d1,
                                              const int* __restrict__ s2,
                                              const int* __restrict__ d2,
                                              int* __restrict__ bcur,
                                              uint2* __restrict__ tmp1,
                                              uint2* __restrict__ tmp2) {
    __shared__ int lhist[NBK], lbase[NBK], gbase[NBK], lcur[NBK];
    __shared__ int sscan[256];
    __shared__ int stot;
    __shared__ uint2 stage[EPB];
    int adj = blockIdx.y;
    const int* ss = adj ? s2 : s1;
    const int* dd = adj ? d2 : d1;
    uint2* tmp = adj ? tmp2 : tmp1;
    int t = threadIdx.x;
    for (int i = t; i < NBK; i += 256) { lhist[i] = 0; lcur[i] = 0; }
    __syncthreads();
    int e0 = blockIdx.x * EPB;
    int d[16], s[16];
    #pragma unroll
    for (int k = 0; k < 16; ++k) {
        int e = e0 + k * 256 + t;
        d[k] = (e < EE) ? dd[e] : -1;
        s[k] = (e < EE) ? ss[e] : 0;
        if (d[k] >= 0) atomicAdd(&lhist[d[k] >> BSH], 1);
    }
    __syncthreads();
    int hv = (t < NBK) ? lhist[t] : 0;
    sscan[t] = hv;
    __syncthreads();
    for (int off = 1; off < 256; off <<= 1) {
        int u = (t >= off) ? sscan[t - off] : 0;
        __syncthreads();
        sscan[t] += u;
        __syncthreads();
    }
    if (t < NBK) lbase[t] = sscan[t] - hv;
    if (t == NBK - 1) stot = sscan[t];
    __syncthreads();
    for (int i = t; i < NBK; i += 256)
        gbase[i] = lhist[i] ? atomicAdd(&bcur[adj * NBK + i], lhist[i]) : 0;
    __syncthreads();
    #pragma unroll
    for (int k = 0; k < 16; ++k) {
        if (d[k] >= 0) {
            int b = d[k] >> BSH;
            int pos = lbase[b] + atomicAdd(&lcur[b], 1);
            stage[pos] = make_uint2((unsigned)d[k], (unsigned)s[k]);
        }
    }
    __syncthreads();
    int tot = stot;
    for (int i = t; i < tot; i += 256) {
        uint2 u = stage[i];
        int b = u.x >> BSH;
        tmp[gbase[b] + (i - lbase[b])] = u;   // chunk-coalesced
    }
}

__global__ __launch_bounds__(256) void binB_k(const uint2* __restrict__ tmp1,
                                              const uint2* __restrict__ tmp2,
                                              const int* __restrict__ bbase,
                                              int* __restrict__ rs1,
                                              int* __restrict__ rs2,
                                              int* __restrict__ csr1,
                                              int* __restrict__ csr2) {
    __shared__ int cnt[512], cur[512];
    __shared__ int sscan[256];
    __shared__ int stage[STG];
    int adj = blockIdx.y, b = blockIdx.x;
    const uint2* tmp = adj ? tmp2 : tmp1;
    int* rs  = adj ? rs2  : rs1;
    int* csr = adj ? csr2 : csr1;
    int t = threadIdx.x;
    int n0 = b << BSH;
    int n1 = n0 + 512; if (n1 > NN) n1 = NN;
    int nn = n1 - n0;
    int base = bbase[adj * (NBK + 1) + b];
    int count = bbase[adj * (NBK + 1) + b + 1] - base;
    cnt[t] = 0; cnt[t + 256] = 0;
    __syncthreads();
    for (int i = t; i < count; i += 256)
        atomicAdd(&cnt[tmp[base + i].x - n0], 1);
    __syncthreads();
    int c0 = cnt[2 * t], c1 = cnt[2 * t + 1];
    int ps = c0 + c1;
    sscan[t] = ps;
    __syncthreads();
    for (int off = 1; off < 256; off <<= 1) {
        int u = (t >= off) ? sscan[t - off] : 0;
        __syncthreads();
        sscan[t] += u;
        __syncthreads();
    }
    int pe = sscan[t] - ps;
    int e0x = pe, e1x = pe + c0;
    if (2 * t < nn)     rs[n0 + 2 * t]     = base + e0x;
    if (2 * t + 1 < nn) rs[n0 + 2 * t + 1] = base + e1x;
    cur[2 * t] = e0x; cur[2 * t + 1] = e1x;
    if (t == 0 && n1 == NN) rs[NN] = base + count;
    __syncthreads();
    for (int i = t; i < count; i += 256) {
        uint2 u = tmp[base + i];
        int loc = atomicAdd(&cur[u.x - n0], 1);
        if (loc < STG) stage[loc] = (int)u.y;
        else csr[base + loc] = (int)u.y;
    }
    __syncthreads();
    int m = count < STG ? count : STG;
    for (int i = t; i < m; i += 256) csr[base + i] = stage[i];
}

// ---------------- W_embed fp32 -> bf16, transposed + chunk-swizzled ----------------

__global__ void wconv_k(const float* __restrict__ W, unsigned short* __restrict__ Wbf) {
    int id = blockIdx.x * 256 + threadIdx.x;
    if (id < 512 * 64) {
        int k = id >> 6, col = id & 63;   // W row-major [512][64]
        int ch = k >> 3, el = k & 7;
        int cs = (ch & ~15) | ((ch & 15) ^ (col & 7));
        Wbf[col * 512 + cs * 8 + el] = f2bf(W[id]);
    }
}

// ---------------- W_cls -> Wbig bf16 [128 cols][192 k], 8-chunk-group swizzle ----------------

__global__ void wcls_k(const float* __restrict__ Wc, unsigned short* __restrict__ Wbig) {
    int id = blockIdx.x * 256 + threadIdx.x;   // 192*128
    int k = id >> 7, col = id & 127;
    float v = 0.f;
    if (col < 40) v = Wc[k * 40 + col];
    else if (col < 80)  { if (k >= 64) v = Wc[(192 + k - 64) * 40 + (col - 40)]; }
    else if (col < 120) { if (k >= 64) v = Wc[(320 + k - 64) * 40 + (col - 80)]; }
    int ch = k >> 3, el = k & 7;
    int phys = (ch & ~7) | ((ch & 7) ^ (col & 7));
    Wbig[col * 192 + phys * 8 + el] = f2bf(v);
}

// ---------------- embed: hcat[:,0:64] = relu(x @ W + b), bf16 MFMA ----------------

__global__ __launch_bounds__(256) void embed_k(const float* __restrict__ x,
                                               const unsigned short* __restrict__ Wbf,
                                               const float* __restrict__ bias,
                                               unsigned short* __restrict__ hcat) {
    __shared__ unsigned short sA[64 * 128];
    __shared__ unsigned short sW[64 * 128];
    int tid = threadIdx.x;
    int lane = tid & 63, wave = tid >> 6;
    int row0 = blockIdx.x * 64;
    f32x4 acc[4];
    #pragma unroll
    for (int n = 0; n < 4; n++) acc[n] = (f32x4){0.f, 0.f, 0.f, 0.f};

    int ccol = tid & 15;
    int rbase = tid >> 4;

    for (int kt = 0; kt < 4; ++kt) {
        #pragma unroll
        for (int rr = 0; rr < 4; ++rr) {
            int r = rbase + rr * 16;
            int grow = row0 + r;
            float v[8];
            if (grow < NN) {
                const float4* px = (const float4*)(x + (size_t)grow * 512 + kt * 128 + ccol * 8);
                float4 p0 = px[0], p1 = px[1];
                v[0] = p0.x; v[1] = p0.y; v[2] = p0.z; v[3] = p0.w;
                v[4] = p1.x; v[5] = p1.y; v[6] = p1.z; v[7] = p1.w;
            } else {
                #pragma unroll
                for (int i = 0; i < 8; i++) v[i] = 0.f;
            }
            unsigned uu[4];
            #pragma unroll
            for (int i = 0; i < 4; i++)
                uu[i] = pack_bf16(v[2 * i], v[2 * i + 1]);
            int cs = ccol ^ (r & 7);
            uint4 pk; pk.x = uu[0]; pk.y = uu[1]; pk.z = uu[2]; pk.w = uu[3];
            *(uint4*)&sA[(r * 16 + cs) * 8] = pk;
        }
        for (int q = tid; q < 1024; q += 256) {
            int col = q >> 4, c = q & 15;
            ((uint4*)sW)[q] = ((const uint4*)Wbf)[col * 64 + kt * 16 + c];
        }
        __syncthreads();
        #pragma unroll
        for (int kk = 0; kk < 4; ++kk) {
            int ar = wave * 16 + (lane & 15);
            int ac = (kk * 4 + (lane >> 4)) ^ (ar & 7);
            frag8 a = *(const frag8*)&sA[(ar * 16 + ac) * 8];
            #pragma unroll
            for (int n = 0; n < 4; n++) {
                int col = n * 16 + (lane & 15);
                int bc = (kk * 4 + (lane >> 4)) ^ (col & 7);
                frag8 b = *(const frag8*)&sW[(col * 16 + bc) * 8];
                acc[n] = __builtin_amdgcn_mfma_f32_16x16x32_bf16(a, b, acc[n], 0, 0, 0);
            }
        }
        __syncthreads();
    }
    #pragma unroll
    for (int n = 0; n < 4; n++) {
        int col = n * 16 + (lane & 15);
        float bv = bias[col];
        #pragma unroll
        for (int i = 0; i < 4; i++) {
            int r = row0 + wave * 16 + (lane >> 4) * 4 + i;
            if (r < NN) {
                float vv = acc[n][i] + bv;
                vv = vv > 0.f ? vv : 0.f;
                hcat[(size_t)r * 192 + col] = f2bf(vv);
            }
        }
    }
}

// ---------------- multi-edge gather helpers: 8-lane groups, uint4 (16B) per lane ----------------

__device__ inline void gacc8(float* a, uint4 u) {
    a[0] += bf2f((unsigned short)(u.x & 0xffff));
    a[1] += bf2f((unsigned short)(u.x >> 16));
    a[2] += bf2f((unsigned short)(u.y & 0xffff));
    a[3] += bf2f((unsigned short)(u.y >> 16));
    a[4] += bf2f((unsigned short)(u.z & 0xffff));
    a[5] += bf2f((unsigned short)(u.z >> 16));
    a[6] += bf2f((unsigned short)(u.w & 0xffff));
    a[7] += bf2f((unsigned short)(u.w >> 16));
}

// ---------------- round 1: hcat[:,64:192] = [A1·h0 | A2·h0]; 8 edges per load ----------------

__global__ __launch_bounds__(256) void round1_k(unsigned short* hc,
                                                const int* __restrict__ rs1,
                                                const int* __restrict__ csr1,
                                                const int* __restrict__ rs2,
                                                const int* __restrict__ csr2) {
    int wave = threadIdx.x >> 6, lane = threadIdx.x & 63;
    int row = blockIdx.x * 4 + wave;
    int g = lane >> 3, gl = lane & 7;

    #pragma unroll
    for (int which = 0; which < 2; ++which) {
        const int* rs  = which ? rs2  : rs1;
        const int* csr = which ? csr2 : csr1;
        int s = rs[row], e = rs[row + 1];
        float a[8] = {0.f, 0.f, 0.f, 0.f, 0.f, 0.f, 0.f, 0.f};
        for (int t0 = s; t0 < e; t0 += 64) {
            int rem = e - t0;
            int idxv = 0;
            if (lane < rem) idxv = csr[t0 + lane];
            int cnt = rem < 64 ? rem : 64;
            int nq = (cnt + 7) >> 3;
            int q = 0;
            for (; q + 2 <= nq; q += 2) {
                int j0 = q * 8 + g, j1 = j0 + 8;
                int s0 = __shfl(idxv, j0);
                int s1 = __shfl(idxv, j1);
                uint4 u0 = *(const uint4*)(hc + (size_t)s0 * 192 + gl * 8);
                uint4 u1 = *(const uint4*)(hc + (size_t)s1 * 192 + gl * 8);
                if (j0 < cnt) gacc8(a, u0);
                if (j1 < cnt) gacc8(a, u1);
            }
            for (; q < nq; ++q) {
                int j0 = q * 8 + g;
                int s0 = __shfl(idxv, j0);
                uint4 u0 = *(const uint4*)(hc + (size_t)s0 * 192 + gl * 8);
                if (j0 < cnt) gacc8(a, u0);
            }
        }
        #pragma unroll
        for (int i = 0; i < 8; ++i) {
            a[i] += __shfl_xor(a[i], 8);
            a[i] += __shfl_xor(a[i], 16);
            a[i] += __shfl_xor(a[i], 32);
        }
        if (lane < 8) {
            uint4 o;
            o.x = pack_bf16(a[0], a[1]);
            o.y = pack_bf16(a[2], a[3]);
            o.z = pack_bf16(a[4], a[5]);
            o.w = pack_bf16(a[6], a[7]);
            *(uint4*)(hc + (size_t)row * 192 + 64 + which * 64 + lane * 8) = o;
        }
    }
}

// ---------------- gemm: [logits | z1 | z2] = hcat(Nx192) @ Wbig(192x120); z -> bf16 zcat ----------------

__global__ __launch_bounds__(256) void gemm_k(const unsigned short* __restrict__ hcat,
                                              const unsigned short* __restrict__ Wbig,
                                              const float* __restrict__ bc,
                                              float* __restrict__ logits,
                                              unsigned short* __restrict__ zcat) {
    __shared__ unsigned short sA[64 * 64];
    __shared__ unsigned short sB[128 * 64];
    int tid = threadIdx.x;
    int lane = tid & 63, wave = tid >> 6;
    int row0 = blockIdx.x * 64;
    f32x4 acc[8];
    #pragma unroll
    for (int n = 0; n < 8; n++) acc[n] = (f32x4){0.f, 0.f, 0.f, 0.f};

    for (int kt = 0; kt < 3; ++kt) {
        #pragma unroll
        for (int q = tid; q < 512; q += 256) {
            int r = q >> 3, c = q & 7;
            int phys = c ^ (r & 7);
            ((uint4*)sA)[r * 8 + phys] = ((const uint4*)hcat)[(size_t)(row0 + r) * 24 + kt * 8 + c];
        }
        #pragma unroll
        for (int q = tid; q < 1024; q += 256) {
            int col = q >> 3, c = q & 7;
            ((uint4*)sB)[q] = ((const uint4*)Wbig)[col * 24 + kt * 8 + c];
        }
        __syncthreads();
        #pragma unroll
        for (int kk = 0; kk < 2; ++kk) {
            int ar = wave * 16 + (lane & 15);
            int ac = (kk * 4 + (lane >> 4)) ^ (ar & 7);
            frag8 a = *(const frag8*)&sA[(ar * 8 + ac) * 8];
            #pragma unroll
            for (int n = 0; n < 8; n++) {
                int col = n * 16 + (lane & 15);
                int bcc = (kk * 4 + (lane >> 4)) ^ (col & 7);
                frag8 b = *(const frag8*)&sB[(col * 8 + bcc) * 8];
                acc[n] = __builtin_amdgcn_mfma_f32_16x16x32_bf16(a, b, acc[n], 0, 0, 0);
            }
        }
        __syncthreads();
    }
    #pragma unroll
    for (int n = 0; n < 8; n++) {
        int col = n * 16 + (lane & 15);
        float bv = (col < 40) ? bc[col] : 0.f;
        #pragma unroll
        for (int i = 0; i < 4; i++) {
            int r = row0 + wave * 16 + (lane >> 4) * 4 + i;
            if (r < NN) {
                float vv = acc[n][i];
                if (col < 40) {
                    logits[(size_t)r * 40 + col] = vv + bv;
                } else if (col < 80) {
                    zcat[(size_t)r * 128 + (col - 40)] = f2bf(vv);        // z1: ushorts 0..39
                } else if (col < 120) {
                    zcat[(size_t)r * 128 + 64 + (col - 80)] = f2bf(vv);   // z2: ushorts 64..103
                }
            }
        }
    }
}

// ---------------- round 2: logits += A1·z1 + A2·z2; log_softmax; 8 edges per load ----------------

__global__ __launch_bounds__(256) void round2_k(const unsigned short* __restrict__ zc,
                                                const int* __restrict__ rs1,
                                                const int* __restrict__ csr1,
                                                const int* __restrict__ rs2,
                                                const int* __restrict__ csr2,
                                                float* __restrict__ logits) {
    int wave = threadIdx.x >> 6, lane = threadIdx.x & 63;
    int row = blockIdx.x * 4 + wave;
    int g = lane >> 3, gl = lane & 7;

    float a[8] = {0.f, 0.f, 0.f, 0.f, 0.f, 0.f, 0.f, 0.f};
    #pragma unroll
    for (int which = 0; which < 2; ++which) {
        const int* rs  = which ? rs2  : rs1;
        const int* csr = which ? csr2 : csr1;
        int s = rs[row], e = rs[row + 1];
        size_t zoff = which * 64 + gl * 8;
        for (int t0 = s; t0 < e; t0 += 64) {
            int rem = e - t0;
            int idxv = 0;
            if (lane < rem) idxv = csr[t0 + lane];
            int cnt = rem < 64 ? rem : 64;
            int nq = (cnt + 7) >> 3;
            int q = 0;
            for (; q + 2 <= nq; q += 2) {
                int j0 = q * 8 + g, j1 = j0 + 8;
                int s0 = __shfl(idxv, j0);
                int s1 = __shfl(idxv, j1);
                uint4 u0 = *(const uint4*)(zc + (size_t)s0 * 128 + zoff);
                uint4 u1 = *(const uint4*)(zc + (size_t)s1 * 128 + zoff);
                if (j0 < cnt) gacc8(a, u0);
                if (j1 < cnt) gacc8(a, u1);
            }
            for (; q < nq; ++q) {
                int j0 = q * 8 + g;
                int s0 = __shfl(idxv, j0);
                uint4 u0 = *(const uint4*)(zc + (size_t)s0 * 128 + zoff);
                if (j0 < cnt) gacc8(a, u0);
            }
        }
    }
    #pragma unroll
    for (int i = 0; i < 8; ++i) {
        a[i] += __shfl_xor(a[i], 8);
        a[i] += __shfl_xor(a[i], 16);
        a[i] += __shfl_xor(a[i], 32);
    }

    // lanes 0..4 hold logits deltas for features 8*lane .. 8*lane+7
    bool act = lane < 5;
    float v[8];
    if (act) {
        float4 b0 = *(const float4*)(logits + (size_t)row * 40 + lane * 8);
        float4 b1 = *(const float4*)(logits + (size_t)row * 40 + lane * 8 + 4);
        v[0] = b0.x + a[0]; v[1] = b0.y + a[1]; v[2] = b0.z + a[2]; v[3] = b0.w + a[3];
        v[4] = b1.x + a[4]; v[5] = b1.y + a[5]; v[6] = b1.z + a[6]; v[7] = b1.w + a[7];
    } else {
        #pragma unroll
        for (int i = 0; i < 8; ++i) v[i] = -1e30f;
    }
    float m = fmaxf(fmaxf(fmaxf(v[0], v[1]), fmaxf(v[2], v[3])),
                    fmaxf(fmaxf(v[4], v[5]), fmaxf(v[6], v[7])));
    m = fmaxf(m, __shfl_xor(m, 1));
    m = fmaxf(m, __shfl_xor(m, 2));
    m = fmaxf(m, __shfl_xor(m, 4));
    float es = 0.f;
    if (act) {
        #pragma unroll
        for (int i = 0; i < 8; ++i) es += __expf(v[i] - m);
    }
    es += __shfl_xor(es, 1);
    es += __shfl_xor(es, 2);
    es += __shfl_xor(es, 4);
    float ls = __logf(es);
    if (act) {
        float4 o0, o1;
        o0.x = v[0] - m - ls; o0.y = v[1] - m - ls; o0.z = v[2] - m - ls; o0.w = v[3] - m - ls;
        o1.x = v[4] - m - ls; o1.y = v[5] - m - ls; o1.z = v[6] - m - ls; o1.w = v[7] - m - ls;
        *(float4*)(logits + (size_t)row * 40 + lane * 8)     = o0;
        *(float4*)(logits + (size_t)row * 40 + lane * 8 + 4) = o1;
    }
}

// ---------------- launch ----------------

extern "C" void kernel_launch(void* const* d_in, const int* in_sizes, int n_in,
                              void* d_out, int out_size, void* d_ws, size_t ws_size,
                              hipStream_t stream) {
    const float* x       = (const float*)d_in[0];
    const float* W_embed = (const float*)d_in[1];
    const float* b_embed = (const float*)d_in[2];
    const float* W_cls   = (const float*)d_in[3];
    const float* b_cls   = (const float*)d_in[4];
    const int* a1src = (const int*)d_in[5];
    const int* a1dst = (const int*)d_in[6];
    const int* a2src = (const int*)d_in[7];
    const int* a2dst = (const int*)d_in[8];

    float* logits = (float*)d_out;
    float* ws = (float*)d_ws;

    // ws layout (units: 4B elements)
    const size_t OFF_HCAT = 0;          // N*192 bf16 = 9.6M floats (overlays tmp1/tmp2)
    const size_t OFF_ZCAT = 9600000;    // N*128 bf16 = 6.4M floats
    const size_t OFF_RS1  = 16000000;   // N+1 ints
    const size_t OFF_RS2  = 16100004;   // N+1 ints
    const size_t OFF_BB   = 16200008;   // bucketBase 2 x 197
    const size_t OFF_BC   = 16200402;   // bcur 2 x 196
    const size_t OFF_BCNT = 16200794;   // bucketCnt 2 x 196
    const size_t OFF_CSR1 = 16201188;   // E ints
    const size_t OFF_CSR2 = 17801188;   // E ints
    const size_t OFF_WBF  = 19401188;   // 32768 ushorts
    const size_t OFF_WBIG = 19417572;   // 24576 ushorts

    unsigned short* hcat = (unsigned short*)(ws + OFF_HCAT);
    unsigned short* zcat = (unsigned short*)(ws + OFF_ZCAT);
    uint2* tmp1 = (uint2*)(ws + OFF_HCAT);        // overlay: used only before embed
    uint2* tmp2 = tmp1 + EE;
    int* rs1   = (int*)(ws + OFF_RS1);
    int* rs2   = (int*)(ws + OFF_RS2);
    int* bbase = (int*)(ws + OFF_BB);
    int* bcur  = (int*)(ws + OFF_BC);
    int* bcnt  = (int*)(ws + OFF_BCNT);
    int* csr1  = (int*)(ws + OFF_CSR1);
    int* csr2  = (int*)(ws + OFF_CSR2);
    unsigned short* wbf  = (unsigned short*)(ws + OFF_WBF);
    unsigned short* wbig = (unsigned short*)(ws + OFF_WBIG);

    hipMemsetAsync(ws + OFF_BCNT, 0, 392 * 4, stream);

    const int NBA = (EE + EPB - 1) / EPB;   // 391

    bhist_k<<<dim3(NBA, 2), 256, 0, stream>>>(a1dst, a2dst, bcnt);
    bscan_k<<<2, 256, 0, stream>>>(bcnt, bbase, bcur);
    binA_k<<<dim3(NBA, 2), 256, 0, stream>>>(a1src, a1dst, a2src, a2dst, bcur, tmp1, tmp2);
    binB_k<<<dim3(NBK, 2), 256, 0, stream>>>(tmp1, tmp2, bbase, rs1, rs2, csr1, csr2);

    wconv_k<<<128, 256, 0, stream>>>(W_embed, wbf);
    wcls_k<<<96, 256, 0, stream>>>(W_cls, wbig);
    embed_k<<<(NN + 63) / 64, 256, 0, stream>>>(x, wbf, b_embed, hcat);

    round1_k<<<NN / 4, 256, 0, stream>>>(hcat, rs1, csr1, rs2, csr2);
    gemm_k<<<(NN + 63) / 64, 256, 0, stream>>>(hcat, wbig, b_cls, logits, zcat);
    round2_k<<<NN / 4, 256, 0, stream>>>(zcat, rs1, csr1, rs2, csr2, logits);
}